// Round 4
// baseline (400.600 us; speedup 1.0000x reference)
//
#include <hip/hip_runtime.h>

typedef unsigned short u16;
typedef __attribute__((ext_vector_type(8))) short bf16x8;
typedef __attribute__((ext_vector_type(16))) float f32x16;

// ---------- bf16 split helpers ----------
__device__ __forceinline__ u16 f2bf_rne(float f) {
  unsigned u = __float_as_uint(f);
  u += 0x7fffu + ((u >> 16) & 1u);
  return (u16)(u >> 16);
}
__device__ __forceinline__ float bf2f(u16 h) {
  return __uint_as_float(((unsigned)h) << 16);
}
__device__ __forceinline__ void split1(float v, u16& h, u16& l) {
  u16 hh = f2bf_rne(v);
  h = hh;
  l = f2bf_rne(v - bf2f(hh));
}

// ---------- global -> LDS async 16B ----------
__device__ __forceinline__ void gl16(const void* g, void* l) {
  __builtin_amdgcn_global_load_lds(
      (const __attribute__((address_space(1))) unsigned int*)g,
      (__attribute__((address_space(3))) unsigned int*)l,
      16, 0, 0);
}

// ---------- merged split-convert for all three inputs (vec4) ----------
__global__ void split_convert_all(const float4* __restrict__ x,
                                  ushort4* __restrict__ xhi, ushort4* __restrict__ xlo,
                                  const float4* __restrict__ wq,
                                  ushort4* __restrict__ wqh, ushort4* __restrict__ wql,
                                  const float4* __restrict__ wo,
                                  ushort4* __restrict__ woh, ushort4* __restrict__ wol) {
  int i = blockIdx.x * 256 + threadIdx.x;
  const float4* src;
  ushort4 *dh, *dl;
  int idx;
  if (i < 3145728) { src = x; dh = xhi; dl = xlo; idx = i; }
  else if (i < 3588096) { src = wq; dh = wqh; dl = wql; idx = i - 3145728; }
  else if (i < 3735552) { src = wo; dh = woh; dl = wol; idx = i - 3588096; }
  else return;
  float4 v = src[idx];
  ushort4 h, l;
  split1(v.x, h.x, l.x); split1(v.y, h.y, l.y);
  split1(v.z, h.z, l.z); split1(v.w, h.w, l.w);
  dh[idx] = h; dl[idx] = l;
}

// ---------- split-bf16 GEMM: C[M,N] = A[M,K] * B[N,K]^T (both K-major) ----------
// 128x128 tile, BK=64, 4 waves (2x2), each wave 64x64 via 2x2 mfma_f32_32x32x16_bf16
// (half the MFMA instruction count of the 16x16 version; measured ceiling 2382 vs
// 2075 TF). 3 MFMAs per fragment pair: hi*hi + hi*lo + lo*hi (~2^-17 product error).
// LDS XOR swizzle (rows are 128 B = 8 x 16B chunks): physical chunk p of row r
// holds logical chunk p ^ (r&7) -> conflict-free reads (R2/R3 measured 0).
__global__ __launch_bounds__(256, 2) void gemm_split_bt(
    const u16* __restrict__ Ahi, const u16* __restrict__ Alo,
    const u16* __restrict__ Bhi, const u16* __restrict__ Blo,
    float* __restrict__ C, int M, int N, int K) {
  __shared__ __align__(16) u16 sAh[128 * 64], sAl[128 * 64], sBh[128 * 64], sBl[128 * 64];
  const int tid = threadIdx.x;
  const int wave = tid >> 6;
  const int lane = tid & 63;
  const int tm0 = blockIdx.x * 128;
  const int tn0 = blockIdx.y * 128;
  const int wm = (wave & 1) * 64;
  const int wn = (wave >> 1) * 64;

  // staging: per wave 4 gl16 per array; each covers 8 rows (128 B/row, 8 lanes/row)
  const int srow = wave * 32 + (lane >> 3);
  const int c = lane & 7;
  const int scol = (c ^ ((lane >> 3) & 7)) * 8;  // XOR-swizzled source chunk
  const u16* gAh = Ahi + (size_t)(tm0 + srow) * K + scol;
  const u16* gAl = Alo + (size_t)(tm0 + srow) * K + scol;
  const u16* gBh = Bhi + (size_t)(tn0 + srow) * K + scol;
  const u16* gBl = Blo + (size_t)(tn0 + srow) * K + scol;
  u16* lAh = &sAh[wave * 32 * 64];
  u16* lAl = &sAl[wave * 32 * 64];
  u16* lBh = &sBh[wave * 32 * 64];
  u16* lBl = &sBl[wave * 32 * 64];
  const size_t rstep8 = (size_t)8 * K;  // 8 rows per gl16

  f32x16 acc[2][2] = {};
  const int m32 = lane & 31;   // row within 32-tile (A and B operand)
  const int half = lane >> 5;  // k-half within 16-k window

  for (int kt = 0; kt < K; kt += 64) {
#pragma unroll
    for (int r = 0; r < 4; ++r) {
      gl16(gAh + kt + r * rstep8, lAh + r * 512);
      gl16(gAl + kt + r * rstep8, lAl + r * 512);
      gl16(gBh + kt + r * rstep8, lBh + r * 512);
      gl16(gBl + kt + r * rstep8, lBl + r * 512);
    }
    __syncthreads();
#pragma unroll
    for (int ks = 0; ks < 4; ++ks) {  // four 16-k steps in BK=64
      const int p = ((ks * 2 + half) ^ (lane & 7)) * 8;  // physical 16B chunk * 8 u16
      bf16x8 ah[2], al[2], bh[2], bl[2];
#pragma unroll
      for (int i = 0; i < 2; ++i) {
        ah[i] = *(const bf16x8*)&sAh[(wm + i * 32 + m32) * 64 + p];
        al[i] = *(const bf16x8*)&sAl[(wm + i * 32 + m32) * 64 + p];
        bh[i] = *(const bf16x8*)&sBh[(wn + i * 32 + m32) * 64 + p];
        bl[i] = *(const bf16x8*)&sBl[(wn + i * 32 + m32) * 64 + p];
      }
#pragma unroll
      for (int i = 0; i < 2; ++i)
#pragma unroll
        for (int j = 0; j < 2; ++j) {
          acc[i][j] = __builtin_amdgcn_mfma_f32_32x32x16_bf16(ah[i], bh[j], acc[i][j], 0, 0, 0);
          acc[i][j] = __builtin_amdgcn_mfma_f32_32x32x16_bf16(ah[i], bl[j], acc[i][j], 0, 0, 0);
          acc[i][j] = __builtin_amdgcn_mfma_f32_32x32x16_bf16(al[i], bh[j], acc[i][j], 0, 0, 0);
        }
    }
    __syncthreads();
  }

  // C/D layout (verified m74/m101): col = lane&31, row = (reg&3) + 8*(reg>>2) + 4*(lane>>5)
  const int col = lane & 31;
#pragma unroll
  for (int i = 0; i < 2; ++i)
#pragma unroll
    for (int j = 0; j < 2; ++j)
#pragma unroll
      for (int r = 0; r < 16; ++r) {
        int rl = (r & 3) + 8 * (r >> 2) + 4 * half;
        C[(size_t)(tm0 + wm + i * 32 + rl) * N + (tn0 + wn + j * 32 + col)] = acc[i][j][r];
      }
}

// ---------- fused dilated attention (+ column partial sums) ----------
// One block per (b, i0): tokens T_j = i0 + 2048*j, j=0..3. All 3 branches fold into
// a 4x4 combination matrix A per head. rows stride padded 2304->2312 so the 4
// j-planes sit 8 banks apart (score-phase k reads were 4-way conflicted).
// Output phase also accumulates per-column partials into Spart[b][i0&63][c].
__global__ __launch_bounds__(256) void attn_dilated(const float* __restrict__ qkv,
                                                    float* __restrict__ out,
                                                    float* __restrict__ Spart) {
  __shared__ float rows[4][2312];
  __shared__ float sc[12][16];
  __shared__ float Aw[12][16];
  const int t = threadIdx.x;
  const int i0 = blockIdx.x;  // 0..2047
  const int b = blockIdx.y;   // 0..1
  const size_t rowbase = (size_t)b * 8192 + i0;

  for (int idx = t; idx < 4 * 576; idx += 256) {
    int j = idx / 576, c4 = idx - j * 576;
    ((float4*)rows[j])[c4] = ((const float4*)(qkv + (rowbase + 2048 * j) * 2304))[c4];
  }
  __syncthreads();

  if (t < 192) {  // scores: q_j . k_jp / 8  (float4 LDS reads)
    int h = t >> 4, j = (t >> 2) & 3, jp = t & 3;
    const float4* q = (const float4*)&rows[j][h * 64];
    const float4* k = (const float4*)&rows[jp][768 + h * 64];
    float s = 0.f;
#pragma unroll
    for (int d = 0; d < 16; ++d) {
      float4 a = q[d], bb = k[d];
      s += a.x * bb.x + a.y * bb.y + a.z * bb.z + a.w * bb.w;
    }
    sc[h][(j << 2) | jp] = s * 0.125f;
  }
  __syncthreads();

  if (t < 48) {  // combine branch weights
    int h = t >> 2, j = t & 3;
    float s0 = sc[h][j * 4 + 0], s1 = sc[h][j * 4 + 1];
    float s2 = sc[h][j * 4 + 2], s3 = sc[h][j * 4 + 3];
    float m = fmaxf(fmaxf(s0, s1), fmaxf(s2, s3));
    float e0 = expf(s0 - m), e1 = expf(s1 - m), e2 = expf(s2 - m), e3 = expf(s3 - m);
    float inv = 1.f / (e0 + e1 + e2 + e3);
    float a[4] = {e0 * inv, e1 * inv, e2 * inv, e3 * inv};
    if ((i0 & 1) == 0) {
      int p = j ^ 2;
      float ss = sc[h][j * 4 + j], sx = sc[h][j * 4 + p];
      float mm = fmaxf(ss, sx);
      float es = expf(ss - mm), ex = expf(sx - mm);
      float iv = 1.f / (es + ex);
      a[j] += es * iv;
      a[p] += ex * iv;
    }
    if ((i0 & 3) == 0) a[j] += 1.f;
    Aw[h][j * 4 + 0] = a[0]; Aw[h][j * 4 + 1] = a[1];
    Aw[h][j * 4 + 2] = a[2]; Aw[h][j * 4 + 3] = a[3];
  }
  __syncthreads();

  float* sp = Spart + ((size_t)b * 64 + (i0 & 63)) * 768;
#pragma unroll
  for (int rep = 0; rep < 3; ++rep) {
    int cc = rep * 256 + t;  // 0..767
    int h = cc >> 6;
    float ps = 0.f;
#pragma unroll
    for (int j = 0; j < 4; ++j) {
      float v = 0.f;
#pragma unroll
      for (int jp = 0; jp < 4; ++jp) v = fmaf(Aw[h][(j << 2) | jp], rows[jp][1536 + cc], v);
      out[(rowbase + 2048 * j) * 768 + cc] = v;
      ps += v;
    }
    atomicAdd(&sp[cc], ps);
  }
}

// ---------- reduce 64 partial slots -> Sinv = 1/colsum ----------
__global__ void colred(const float* __restrict__ Spart, float* __restrict__ Sinv) {
  int i = blockIdx.x * 256 + threadIdx.x;  // 0..1535
  if (i >= 1536) return;
  int b = i / 768, c = i - b * 768;
  const float* p = Spart + (size_t)b * 64 * 768 + c;
  float s = 0.f;
#pragma unroll
  for (int g = 0; g < 64; ++g) s += p[g * 768];
  Sinv[i] = 1.0f / s;
}

// ---------- normalize by Sinv and split-convert ----------
__global__ void norm_split4(const float4* __restrict__ in, const float* __restrict__ Sinv,
                            ushort4* __restrict__ hi, ushort4* __restrict__ lo, int n4) {
  int i = blockIdx.x * 256 + threadIdx.x;
  if (i >= n4) return;
  int e = i * 4;
  int c = e % 768;
  int b = e / (8192 * 768);
  const float* s = Sinv + b * 768 + c;
  float4 v = in[i];
  v.x *= s[0]; v.y *= s[1]; v.z *= s[2]; v.w *= s[3];
  ushort4 h, l;
  split1(v.x, h.x, l.x); split1(v.y, h.y, l.y);
  split1(v.z, h.z, l.z); split1(v.w, h.w, l.w);
  hi[i] = h; lo[i] = l;
}

extern "C" void kernel_launch(void* const* d_in, const int* in_sizes, int n_in,
                              void* d_out, int out_size, void* d_ws, size_t ws_size,
                              hipStream_t stream) {
  (void)in_sizes; (void)n_in; (void)out_size; (void)ws_size;
  const float* x = (const float*)d_in[0];     // (2,8192,768)
  const float* Wqkv = (const float*)d_in[1];  // (2304,768)
  const float* Wout = (const float*)d_in[2];  // (768,768)
  float* out = (float*)d_out;                 // (2,8192,768) fp32; also attn scratch

  // workspace layout (bytes). qkv region reused for no_hi/no_lo after attention;
  // xhi region reused for Spart/Sinv after GEMM1.
  char* w = (char*)d_ws;
  float* qkv = (float*)(w);                    // 150,994,944
  u16* no_hi = (u16*)(w);                      // 25,165,824 (reuse)
  u16* no_lo = (u16*)(w + 25165824);           // 25,165,824 (reuse)
  size_t off = 150994944;
  u16* xhi = (u16*)(w + off);
  float* Spart = (float*)(w + off);            // [2][64][768] fp32 = 393,216 (reuse of xhi)
  float* Sinv = (float*)(w + off + 393216);    // 6,144 (reuse of xhi)
  off += 25165824;
  u16* xlo = (u16*)(w + off); off += 25165824;
  u16* wqh = (u16*)(w + off); off += 3538944;
  u16* wql = (u16*)(w + off); off += 3538944;
  u16* woh = (u16*)(w + off); off += 1179648;
  u16* wol = (u16*)(w + off); off += 1179648;   // ~201 MB total

  // 1) split-convert all inputs (one launch)
  split_convert_all<<<dim3(14592), 256, 0, stream>>>(
      (const float4*)x, (ushort4*)xhi, (ushort4*)xlo,
      (const float4*)Wqkv, (ushort4*)wqh, (ushort4*)wql,
      (const float4*)Wout, (ushort4*)woh, (ushort4*)wol);

  // 2) qkv = x @ Wqkv^T   (M=16384, N=2304, K=768)
  gemm_split_bt<<<dim3(128, 18), 256, 0, stream>>>(xhi, xlo, wqh, wql, qkv, 16384, 2304, 768);

  // 3) zero partial-sum slots (xhi region now free), then fused attention -> out + Spart
  hipMemsetAsync(Spart, 0, 393216, stream);
  attn_dilated<<<dim3(2048, 2), 256, 0, stream>>>(qkv, out, Spart);

  // 4) reduce partials -> Sinv
  colred<<<dim3(6), 256, 0, stream>>>(Spart, Sinv);

  // 5) normalize + split-convert (reuses qkv region)
  norm_split4<<<dim3((3145728 + 255) / 256), 256, 0, stream>>>(
      (const float4*)out, Sinv, (ushort4*)no_hi, (ushort4*)no_lo, 3145728);

  // 6) out = no @ Wout^T   (M=16384, N=768, K=768)
  gemm_split_bt<<<dim3(128, 6), 256, 0, stream>>>(no_hi, no_lo, woh, wol, out, 16384, 768, 768);
}

// Round 6
// 351.363 us; speedup vs baseline: 1.1401x; 1.1401x over previous
//
#include <hip/hip_runtime.h>

typedef unsigned short u16;
typedef __attribute__((ext_vector_type(8))) short bf16x8;
typedef __attribute__((ext_vector_type(4))) float f32x4;

// ---------- bf16 split helpers ----------
__device__ __forceinline__ u16 f2bf_rne(float f) {
  unsigned u = __float_as_uint(f);
  u += 0x7fffu + ((u >> 16) & 1u);
  return (u16)(u >> 16);
}
__device__ __forceinline__ float bf2f(u16 h) {
  return __uint_as_float(((unsigned)h) << 16);
}
__device__ __forceinline__ void split1(float v, u16& h, u16& l) {
  u16 hh = f2bf_rne(v);
  h = hh;
  l = f2bf_rne(v - bf2f(hh));
}

// ---------- global -> LDS async 16B ----------
__device__ __forceinline__ void gl16(const void* g, void* l) {
  __builtin_amdgcn_global_load_lds(
      (const __attribute__((address_space(1))) unsigned int*)g,
      (__attribute__((address_space(3))) unsigned int*)l,
      16, 0, 0);
}

// ---------- merged split-convert (x and Wqkv) ----------
__global__ void split_convert_all(const float4* __restrict__ x,
                                  ushort4* __restrict__ xhi, ushort4* __restrict__ xlo,
                                  const float4* __restrict__ wq,
                                  ushort4* __restrict__ wqh, ushort4* __restrict__ wql) {
  int i = blockIdx.x * 256 + threadIdx.x;
  const float4* src;
  ushort4 *dh, *dl;
  int idx;
  if (i < 3145728) { src = x; dh = xhi; dl = xlo; idx = i; }
  else if (i < 3588096) { src = wq; dh = wqh; dl = wql; idx = i - 3145728; }
  else return;
  float4 v = src[idx];
  ushort4 h, l;
  split1(v.x, h.x, l.x); split1(v.y, h.y, l.y);
  split1(v.z, h.z, l.z); split1(v.w, h.w, l.w);
  dh[idx] = h; dl[idx] = l;
}

// ---------- split-bf16 GEMM: C[M,N] = A[M,K] * B[N,K]^T ----------
// R3 configuration (155 us, 0 conflicts, MfmaUtil 50%): 128x128 tile, BK=64,
// 4 waves (2x2), each wave 64x64 via 4x4 mfma_f32_16x16x32_bf16, 2 k-sub-blocks.
// 3 MFMAs per fragment pair: hi*hi + hi*lo + lo*hi (~2^-17 product error).
// LDS XOR swizzle: physical chunk p of row r holds logical chunk p ^ (r&7);
// 16-lane reader groups put exactly 2 lanes per bank-quad (2-way = free).
// A has explicit row stride lda (u16 elems) so GEMM2 can read the interleaved
// hi/lo rows written in-place into the qkv region. B stride = K.
// B2 pair: rows with 2*tm0 >= M use Bhi2/Blo2 (per-batch folded weights in GEMM2).
__global__ __launch_bounds__(256, 2) void gemm_split_bt(
    const u16* __restrict__ Ahi, const u16* __restrict__ Alo, int lda,
    const u16* __restrict__ Bhi, const u16* __restrict__ Blo,
    const u16* __restrict__ Bhi2, const u16* __restrict__ Blo2,
    float* __restrict__ C, int M, int N, int K) {
  __shared__ __align__(16) u16 sAh[128 * 64], sAl[128 * 64], sBh[128 * 64], sBl[128 * 64];
  const int tid = threadIdx.x;
  const int wave = tid >> 6;
  const int lane = tid & 63;
  const int tm0 = blockIdx.x * 128;
  const int tn0 = blockIdx.y * 128;
  const int wm = (wave & 1) * 64;
  const int wn = (wave >> 1) * 64;
  if (2 * tm0 >= M) { Bhi = Bhi2; Blo = Blo2; }

  // staging: per wave 4 gl16 per array; each covers 8 rows (128 B/row, 8 lanes/row)
  const int srow = wave * 32 + (lane >> 3);
  const int c = lane & 7;
  const int scol = (c ^ ((lane >> 3) & 7)) * 8;  // XOR-swizzled source chunk
  const u16* gAh = Ahi + (size_t)(tm0 + srow) * lda + scol;
  const u16* gAl = Alo + (size_t)(tm0 + srow) * lda + scol;
  const u16* gBh = Bhi + (size_t)(tn0 + srow) * K + scol;
  const u16* gBl = Blo + (size_t)(tn0 + srow) * K + scol;
  u16* lAh = &sAh[wave * 32 * 64];
  u16* lAl = &sAl[wave * 32 * 64];
  u16* lBh = &sBh[wave * 32 * 64];
  u16* lBl = &sBl[wave * 32 * 64];
  const size_t rstepA = (size_t)8 * lda;  // 8 rows per gl16
  const size_t rstepB = (size_t)8 * K;

  f32x4 acc[4][4] = {};
  const int fr = lane & 15;    // A/B fragment row (m or n within 16-tile)
  const int quad = lane >> 4;  // logical k-chunk within 32-k sub-block

  for (int kt = 0; kt < K; kt += 64) {
#pragma unroll
    for (int r = 0; r < 4; ++r) {
      gl16(gAh + kt + r * rstepA, lAh + r * 512);
      gl16(gAl + kt + r * rstepA, lAl + r * 512);
      gl16(gBh + kt + r * rstepB, lBh + r * 512);
      gl16(gBl + kt + r * rstepB, lBl + r * 512);
    }
    __syncthreads();
    for (int subk = 0; subk < 2; ++subk) {
      const int k0 = ((subk * 4 + quad) ^ (fr & 7)) * 8;  // physical chunk * 8 u16
      bf16x8 ah[4], al[4], bh[4], bl[4];
#pragma unroll
      for (int i = 0; i < 4; ++i) {
        ah[i] = *(const bf16x8*)&sAh[(wm + i * 16 + fr) * 64 + k0];
        al[i] = *(const bf16x8*)&sAl[(wm + i * 16 + fr) * 64 + k0];
        bh[i] = *(const bf16x8*)&sBh[(wn + i * 16 + fr) * 64 + k0];
        bl[i] = *(const bf16x8*)&sBl[(wn + i * 16 + fr) * 64 + k0];
      }
#pragma unroll
      for (int i = 0; i < 4; ++i)
#pragma unroll
        for (int j = 0; j < 4; ++j) {
          acc[i][j] = __builtin_amdgcn_mfma_f32_16x16x32_bf16(ah[i], bh[j], acc[i][j], 0, 0, 0);
          acc[i][j] = __builtin_amdgcn_mfma_f32_16x16x32_bf16(ah[i], bl[j], acc[i][j], 0, 0, 0);
          acc[i][j] = __builtin_amdgcn_mfma_f32_16x16x32_bf16(al[i], bh[j], acc[i][j], 0, 0, 0);
        }
    }
    __syncthreads();
  }

  // C/D layout: col = lane&15, row = (lane>>4)*4 + reg  (verified m89/m91)
  const int col = lane & 15;
  const int rowq = (lane >> 4) * 4;
#pragma unroll
  for (int i = 0; i < 4; ++i)
#pragma unroll
    for (int j = 0; j < 4; ++j) {
      size_t base = (size_t)(tm0 + wm + i * 16 + rowq) * N + (tn0 + wn + j * 16 + col);
#pragma unroll
      for (int r = 0; r < 4; ++r) C[base + (size_t)r * N] = acc[i][j][r];
    }
}

// ---------- fused dilated attention (+ column partial sums, split output IN PLACE) ----------
// One block per (b, i0): tokens T_j = i0 + 2048*j. Branches fold into a 4x4 matrix
// per head. Writes UNNORMALIZED output as bf16 hi/lo splits IN PLACE into the qkv
// region: row t's 9216-byte slot holds hi at u16 offset t*4608, lo at t*4608+768.
// Race-free: each block exclusively owns its 4 token rows and has them in LDS
// before the write phase. (R5 lesson: 16384x768 u16 = 25.17 MB per array — the
// separate-buffer layout overlapped and corrupted batch-0's lo. Size in BYTES.)
__global__ __launch_bounds__(256) void attn_dilated(const float* __restrict__ qkv,
                                                    u16* __restrict__ qk16,
                                                    float* __restrict__ Spart) {
  __shared__ float rows[4][2312];
  __shared__ float sc[12][16];
  __shared__ float Aw[12][16];
  const int t = threadIdx.x;
  const int i0 = blockIdx.x;  // 0..2047
  const int b = blockIdx.y;   // 0..1
  const size_t rowbase = (size_t)b * 8192 + i0;

  for (int idx = t; idx < 4 * 576; idx += 256) {
    int j = idx / 576, c4 = idx - j * 576;
    ((float4*)rows[j])[c4] = ((const float4*)(qkv + (rowbase + 2048 * j) * 2304))[c4];
  }
  __syncthreads();

  if (t < 192) {  // scores: q_j . k_jp / 8  (float4 LDS reads)
    int h = t >> 4, j = (t >> 2) & 3, jp = t & 3;
    const float4* q = (const float4*)&rows[j][h * 64];
    const float4* k = (const float4*)&rows[jp][768 + h * 64];
    float s = 0.f;
#pragma unroll
    for (int d = 0; d < 16; ++d) {
      float4 a = q[d], bb = k[d];
      s += a.x * bb.x + a.y * bb.y + a.z * bb.z + a.w * bb.w;
    }
    sc[h][(j << 2) | jp] = s * 0.125f;
  }
  __syncthreads();

  if (t < 48) {  // combine branch weights
    int h = t >> 2, j = t & 3;
    float s0 = sc[h][j * 4 + 0], s1 = sc[h][j * 4 + 1];
    float s2 = sc[h][j * 4 + 2], s3 = sc[h][j * 4 + 3];
    float m = fmaxf(fmaxf(s0, s1), fmaxf(s2, s3));
    float e0 = expf(s0 - m), e1 = expf(s1 - m), e2 = expf(s2 - m), e3 = expf(s3 - m);
    float inv = 1.f / (e0 + e1 + e2 + e3);
    float a[4] = {e0 * inv, e1 * inv, e2 * inv, e3 * inv};
    if ((i0 & 1) == 0) {
      int p = j ^ 2;
      float ss = sc[h][j * 4 + j], sx = sc[h][j * 4 + p];
      float mm = fmaxf(ss, sx);
      float es = expf(ss - mm), ex = expf(sx - mm);
      float iv = 1.f / (es + ex);
      a[j] += es * iv;
      a[p] += ex * iv;
    }
    if ((i0 & 3) == 0) a[j] += 1.f;
    Aw[h][j * 4 + 0] = a[0]; Aw[h][j * 4 + 1] = a[1];
    Aw[h][j * 4 + 2] = a[2]; Aw[h][j * 4 + 3] = a[3];
  }
  __syncthreads();

  float* sp = Spart + ((size_t)b * 64 + (i0 & 63)) * 768;
#pragma unroll
  for (int rep = 0; rep < 3; ++rep) {
    int cc = rep * 256 + t;  // 0..767
    int h = cc >> 6;
    float ps = 0.f;
#pragma unroll
    for (int j = 0; j < 4; ++j) {
      float v = 0.f;
#pragma unroll
      for (int jp = 0; jp < 4; ++jp) v = fmaf(Aw[h][(j << 2) | jp], rows[jp][1536 + cc], v);
      u16 h16, l16;
      split1(v, h16, l16);
      size_t base = (rowbase + 2048 * j) * 4608;  // u16 offset of row slot
      qk16[base + cc] = h16;
      qk16[base + 768 + cc] = l16;
      ps += v;
    }
    atomicAdd(&sp[cc], ps);
  }
}

// ---------- reduce 64 partial slots -> Sinv = 1/colsum ----------
__global__ void colred(const float* __restrict__ Spart, float* __restrict__ Sinv) {
  int i = blockIdx.x * 256 + threadIdx.x;  // 0..1535
  if (i >= 1536) return;
  int b = i / 768, c = i - b * 768;
  const float* p = Spart + (size_t)b * 64 * 768 + c;
  float s = 0.f;
#pragma unroll
  for (int g = 0; g < 64; ++g) s += p[g * 768];
  Sinv[i] = 1.0f / s;
}

// ---------- fold normalization into Wout: W_b[e,c] = Wout[e,c] * Sinv[b,c], split ----------
__global__ void scale_wout(const float4* __restrict__ Wout, const float* __restrict__ Sinv,
                           ushort4* __restrict__ wh0, ushort4* __restrict__ wl0,
                           ushort4* __restrict__ wh1, ushort4* __restrict__ wl1) {
  int i = blockIdx.x * 256 + threadIdx.x;  // 0..294911 (2 * 147456 float4)
  if (i >= 294912) return;
  int b = i / 147456;
  int r = i - b * 147456;           // float4 index within 768x768
  int c = (r % 192) * 4;            // column of first element
  const float* s = Sinv + b * 768 + c;
  float4 v = Wout[r];
  v.x *= s[0]; v.y *= s[1]; v.z *= s[2]; v.w *= s[3];
  ushort4 h, l;
  split1(v.x, h.x, l.x); split1(v.y, h.y, l.y);
  split1(v.z, h.z, l.z); split1(v.w, h.w, l.w);
  if (b == 0) { wh0[r] = h; wl0[r] = l; }
  else        { wh1[r] = h; wl1[r] = l; }
}

extern "C" void kernel_launch(void* const* d_in, const int* in_sizes, int n_in,
                              void* d_out, int out_size, void* d_ws, size_t ws_size,
                              hipStream_t stream) {
  (void)in_sizes; (void)n_in; (void)out_size; (void)ws_size;
  const float* x = (const float*)d_in[0];     // (2,8192,768)
  const float* Wqkv = (const float*)d_in[1];  // (2304,768)
  const float* Wout = (const float*)d_in[2];  // (768,768)
  float* out = (float*)d_out;                 // (2,8192,768) fp32 final result

  // workspace layout (bytes):
  //  [0, 151MB)       qkv fp32; attn rewrites it in place as split hi/lo rows
  //                   (u16 row stride 4608: hi at +0, lo at +768)
  //  [151MB, +25MB)   xhi  -> after GEMM1: Spart(384K) + Sinv(6K) + W_b splits (4x1.15MB)
  //  [176MB, +25MB)   xlo  (free after GEMM1)
  //  [201MB, +7MB)    wqh, wql
  char* w = (char*)d_ws;
  float* qkv = (float*)(w);
  u16* qk16 = (u16*)(w);
  size_t off = 150994944;
  u16* xhi = (u16*)(w + off);
  float* Spart = (float*)(w + off);              // 393,216 B (reuse of xhi)
  float* Sinv = (float*)(w + off + 393216);      // 6,144 B
  u16* wh0 = (u16*)(w + off + 400000);           // 1,179,648 B each
  u16* wl0 = (u16*)(w + off + 1579648);
  u16* wh1 = (u16*)(w + off + 2759296);
  u16* wl1 = (u16*)(w + off + 3938944);
  off += 25165824;
  u16* xlo = (u16*)(w + off); off += 25165824;
  u16* wqh = (u16*)(w + off); off += 3538944;
  u16* wql = (u16*)(w + off); off += 3538944;    // ~208 MB total (same as R4)

  // 1) split-convert x and Wqkv
  split_convert_all<<<dim3(14016), 256, 0, stream>>>(
      (const float4*)x, (ushort4*)xhi, (ushort4*)xlo,
      (const float4*)Wqkv, (ushort4*)wqh, (ushort4*)wql);

  // 2) qkv = x @ Wqkv^T   (M=16384, N=2304, K=768)
  gemm_split_bt<<<dim3(128, 18), 256, 0, stream>>>(xhi, xlo, 768, wqh, wql, wqh, wql,
                                                   qkv, 16384, 2304, 768);

  // 3) zero partial-sum slots (xhi free now), fused attention:
  //    reads fp32 qkv rows, writes unnormalized hi/lo splits in place + Spart
  hipMemsetAsync(Spart, 0, 393216, stream);
  attn_dilated<<<dim3(2048, 2), 256, 0, stream>>>(qkv, qk16, Spart);

  // 4) reduce partials -> Sinv
  colred<<<dim3(6), 256, 0, stream>>>(Spart, Sinv);

  // 5) fold 1/S into Wout per batch, split to bf16 hi/lo
  scale_wout<<<dim3(1152), 256, 0, stream>>>((const float4*)Wout, Sinv,
                                             (ushort4*)wh0, (ushort4*)wl0,
                                             (ushort4*)wh1, (ushort4*)wl1);

  // 6) out = no @ W_b^T   (M=16384, N=768, K=768; A strided in qkv region)
  gemm_split_bt<<<dim3(128, 6), 256, 0, stream>>>(qk16, qk16 + 768, 4608,
                                                  wh0, wl0, wh1, wl1,
                                                  out, 16384, 768, 768);
}